// Round 1
// baseline (99.056 us; speedup 1.0000x reference)
//
#include <hip/hip_runtime.h>
#include <hip/hip_bf16.h>
#include <cstddef>
#include <cstdint>

#define BB 4
#define NN 4096
#define CC 64
#define DD 32
#define NPIX (BB*NN)   // 16384
#define EPSV 1e-3f

using f32x4 = __attribute__((ext_vector_type(4))) float;
using bh8   = __attribute__((ext_vector_type(8))) short;   // 8 bf16 in 4 VGPRs

// ---------------------------------------------------------------------------
// Kernel 1: projections.  theta/phi stored [pix][32] bf16; g stored transposed
// [b][32][4096] bf16 (so PV's B-fragment reads 8 contiguous keys per lane).
// ---------------------------------------------------------------------------
__global__ __launch_bounds__(256) void proj_kernel(
    const float* __restrict__ x,
    const float* __restrict__ gW, const float* __restrict__ gbias,
    const float* __restrict__ pW, const float* __restrict__ pbias,
    const float* __restrict__ tW, const float* __restrict__ tbias,
    __hip_bfloat16* __restrict__ thetab,
    __hip_bfloat16* __restrict__ phib,
    __hip_bfloat16* __restrict__ gtb)
{
    __shared__ float lx[64*65];        // 64 pixels x 64 ch, padded
    __shared__ float lw[3*64*32];      // theta, phi, g
    __shared__ float lbias[96];
    const int tid = threadIdx.x;
    const int pix0 = blockIdx.x * 64;

    #pragma unroll
    for (int j = 0; j < 16; ++j) {
        int idx = tid + 256*j;
        int p = idx >> 6, c = idx & 63;
        lx[p*65 + c] = x[(size_t)(pix0 + p)*64 + c];
    }
    #pragma unroll
    for (int j = 0; j < 8; ++j) {
        int idx = tid + 256*j;
        lw[idx]        = tW[idx];
        lw[2048 + idx] = pW[idx];
        lw[4096 + idx] = gW[idx];
    }
    if (tid < 32) { lbias[tid] = tbias[tid]; lbias[32+tid] = pbias[tid]; lbias[64+tid] = gbias[tid]; }
    __syncthreads();

    const int p  = tid & 63;
    const int og = tid >> 6;            // 0..3 -> 24 outputs each (96 total)
    float xr[64];
    #pragma unroll
    for (int c = 0; c < 64; ++c) xr[c] = lx[p*65 + c];
    float acc[24];
    #pragma unroll
    for (int j = 0; j < 24; ++j) acc[j] = 0.f;
    const int obase = og*24;
    for (int c = 0; c < 64; ++c) {
        float xc = xr[c];
        #pragma unroll
        for (int j = 0; j < 24; ++j) {
            int o = obase + j;
            acc[j] += xc * lw[(o >> 5)*2048 + c*32 + (o & 31)];
        }
    }
    const int pix = pix0 + p;
    const int b = pix >> 12;
    const int n = pix & 4095;
    #pragma unroll
    for (int j = 0; j < 24; ++j) {
        int o = obase + j;
        __hip_bfloat16 bv = __float2bfloat16(acc[j] + lbias[o]);
        if (o < 32)       thetab[(size_t)pix*32 + o] = bv;
        else if (o < 64)  phib[(size_t)pix*32 + (o-32)] = bv;
        else              gtb[((size_t)b*32 + (o-64))*4096 + n] = bv;
    }
}

// ---------------------------------------------------------------------------
// Kernel 2: flash attention, max-free softmax, split-K=2.
// grid = B * 64 qtiles * 2 splits = 512 blocks; 4 waves/block, 16 queries/wave.
// Outputs UNNORMALIZED y-partials and l-partials (they just add across splits).
// ---------------------------------------------------------------------------
__global__ __launch_bounds__(256) void attn_kernel(
    const __hip_bfloat16* __restrict__ thetab,
    const __hip_bfloat16* __restrict__ phib,
    const __hip_bfloat16* __restrict__ gtb,
    float* __restrict__ ypart, float* __restrict__ lpart)
{
    __shared__ __align__(16) __hip_bfloat16 Pl[4][16][40];  // per-wave P tile, 80B rows
    const int tid  = threadIdx.x;
    const int wave = tid >> 6;
    const int lane = tid & 63;
    const int h = lane >> 4;      // 0..3
    const int r = lane & 15;      // 0..15
    const int blk = blockIdx.x;
    const int split = blk & 1;
    const int bq = blk >> 1;
    const int b = bq >> 6;
    const int qtile = bq & 63;
    const int q0 = qtile*64 + wave*16;
    const int base = b*4096;

    // Q A-fragment: row = lane&15, k-slots = 8*(lane>>4)+i (contiguous)
    bh8 qa = *(const bh8*)(thetab + ((size_t)(base + q0 + r))*32 + h*8);

    f32x4 yacc0 = {0.f,0.f,0.f,0.f};
    f32x4 yacc1 = {0.f,0.f,0.f,0.f};
    float ls0 = 0.f, ls1 = 0.f, ls2 = 0.f, ls3 = 0.f;

    const __hip_bfloat16* phiB = phib + (size_t)base*32;
    const __hip_bfloat16* gtB  = gtb  + (size_t)b*32*4096;

    const int kbeg = split*2048;
    const int kend = kbeg + 2048;
    for (int kk = kbeg; kk < kend; kk += 32) {
        #pragma unroll
        for (int t = 0; t < 2; ++t) {
            const int k0 = kk + t*16;
            bh8 kb = *(const bh8*)(phiB + ((size_t)(k0 + r))*32 + h*8);
            f32x4 zero = {0.f,0.f,0.f,0.f};
            // S[q=4h+reg][k = k0 + r]  (C/D layout verified m89/m91)
            f32x4 s = __builtin_amdgcn_mfma_f32_16x16x32_bf16(qa, kb, zero, 0, 0, 0);
            float p0 = __expf(s[0]); float p1 = __expf(s[1]);
            float p2 = __expf(s[2]); float p3 = __expf(s[3]);
            ls0 += p0; ls1 += p1; ls2 += p2; ls3 += p3;
            Pl[wave][4*h+0][t*16+r] = __float2bfloat16(p0);
            Pl[wave][4*h+1][t*16+r] = __float2bfloat16(p1);
            Pl[wave][4*h+2][t*16+r] = __float2bfloat16(p2);
            Pl[wave][4*h+3][t*16+r] = __float2bfloat16(p3);
        }
        // G B-fragments: col = d = lane&15 (per 16-dim tile), k-slots contiguous keys
        bh8 g0 = *(const bh8*)(gtB + ((size_t)(0*16 + r))*4096 + kk + h*8);
        bh8 g1 = *(const bh8*)(gtB + ((size_t)(1*16 + r))*4096 + kk + h*8);
        // P A-fragment: row = q = lane&15, k-slots = 8h+i local keys (same kmap as B)
        bh8 pa = *(const bh8*)(&Pl[wave][r][h*8]);
        yacc0 = __builtin_amdgcn_mfma_f32_16x16x32_bf16(pa, g0, yacc0, 0, 0, 0);
        yacc1 = __builtin_amdgcn_mfma_f32_16x16x32_bf16(pa, g1, yacc1, 0, 0, 0);
    }

    float ls[4] = {ls0, ls1, ls2, ls3};
    #pragma unroll
    for (int gi = 0; gi < 4; ++gi) {
        float l = ls[gi];
        l += __shfl_xor(l, 1, 16);
        l += __shfl_xor(l, 2, 16);
        l += __shfl_xor(l, 4, 16);
        l += __shfl_xor(l, 8, 16);
        ls[gi] = l;
    }
    float* yo = ypart + (size_t)split*((size_t)NPIX*32);
    float* lo = lpart + (size_t)split*NPIX;
    #pragma unroll
    for (int gi = 0; gi < 4; ++gi) {
        int q = base + q0 + 4*h + gi;
        yo[(size_t)q*32 + r]      = yacc0[gi];
        yo[(size_t)q*32 + 16 + r] = yacc1[gi];
        if (r == 0) lo[q] = ls[gi];
    }
}

// ---------------------------------------------------------------------------
// Kernel 3: combine splits, normalize, w_y = y @ w_W + w_b -> d_out (temp),
// and per-channel sum / sumsq partials via atomics.
// ---------------------------------------------------------------------------
__global__ __launch_bounds__(256) void wy_kernel(
    const float* __restrict__ y0, const float* __restrict__ y1,
    const float* __restrict__ l0, const float* __restrict__ l1,
    const float* __restrict__ wW, const float* __restrict__ wb,
    float* __restrict__ out, float* __restrict__ stats)
{
    __shared__ float ly[128*33];
    __shared__ float linv[128];
    __shared__ float lwW[32*64];
    __shared__ float lwb[64];
    __shared__ float wy[128*65];
    __shared__ float red[8*64];
    const int tid = threadIdx.x;
    const int pix0 = blockIdx.x * 128;

    #pragma unroll
    for (int j = 0; j < 16; ++j) {   // 128*32 / 256
        int idx = tid + 256*j;
        int p = idx >> 5, d = idx & 31;
        size_t gi = (size_t)(pix0+p)*32 + d;
        ly[p*33 + d] = y0[gi] + y1[gi];
    }
    if (tid < 128) linv[tid] = 1.0f / (l0[pix0+tid] + l1[pix0+tid]);
    #pragma unroll
    for (int j = 0; j < 8; ++j) lwW[tid + 256*j] = wW[tid + 256*j];
    if (tid < 64) lwb[tid] = wb[tid];
    __syncthreads();

    const int p  = tid & 127;
    const int ch = tid >> 7;     // 0/1 -> channels [ch*32, ch*32+32)
    float yr[32];
    {
        float li = linv[p];
        #pragma unroll
        for (int d = 0; d < 32; ++d) yr[d] = ly[p*33 + d] * li;
    }
    for (int j = 0; j < 32; ++j) {
        int c = ch*32 + j;
        float acc = lwb[c];
        #pragma unroll
        for (int d = 0; d < 32; ++d) acc += yr[d] * lwW[d*64 + c];
        wy[p*65 + c] = acc;
    }
    __syncthreads();

    #pragma unroll
    for (int j = 0; j < 32; ++j) {
        int idx = tid + 256*j;   // 8192 outputs
        out[(size_t)pix0*64 + idx] = wy[(idx >> 6)*65 + (idx & 63)];
    }
    const int c = tid & 63, qq = tid >> 6;
    float s1 = 0.f, s2 = 0.f;
    for (int pp = qq*32; pp < qq*32 + 32; ++pp) {
        float v = wy[pp*65 + c];
        s1 += v; s2 += v*v;
    }
    red[qq*64 + c] = s1;
    red[(4+qq)*64 + c] = s2;
    __syncthreads();
    if (tid < 64) {
        float t1 = red[tid] + red[64+tid] + red[128+tid] + red[192+tid];
        float t2 = red[256+tid] + red[320+tid] + red[384+tid] + red[448+tid];
        atomicAdd(&stats[tid], t1);
        atomicAdd(&stats[64+tid], t2);
    }
}

// ---------------------------------------------------------------------------
// Kernel 4: BN finalize: scale/shift per channel.
// ---------------------------------------------------------------------------
__global__ void bn_finalize(const float* __restrict__ stats,
                            const float* __restrict__ gamma,
                            const float* __restrict__ beta,
                            float* __restrict__ params)
{
    int c = threadIdx.x;
    float mean = stats[c] * (1.0f/16384.0f);
    float var  = stats[64+c] * (1.0f/16384.0f) - mean*mean;
    float sc = gamma[c] * rsqrtf(var + EPSV);
    params[c] = sc;
    params[64+c] = beta[c] - mean*sc;
}

// ---------------------------------------------------------------------------
// Kernel 5: out = x + scale[c]*w_y + shift[c]  (w_y currently in d_out)
// ---------------------------------------------------------------------------
__global__ __launch_bounds__(256) void apply_kernel(
    const float* __restrict__ x, const float* __restrict__ params,
    float* __restrict__ out)
{
    int i4 = blockIdx.x*256 + threadIdx.x;      // 262144 float4s
    const float4* x4 = (const float4*)x;
    float4* o4 = (float4*)out;
    int cb = (i4 & 15) * 4;
    float4 v  = o4[i4];
    float4 xv = x4[i4];
    float4 sc = *(const float4*)(params + cb);
    float4 sh = *(const float4*)(params + 64 + cb);
    float4 rr;
    rr.x = xv.x + sc.x*v.x + sh.x;
    rr.y = xv.y + sc.y*v.y + sh.y;
    rr.z = xv.z + sc.z*v.z + sh.z;
    rr.w = xv.w + sc.w*v.w + sh.w;
    o4[i4] = rr;
}

// ---------------------------------------------------------------------------
extern "C" void kernel_launch(void* const* d_in, const int* in_sizes, int n_in,
                              void* d_out, int out_size, void* d_ws, size_t ws_size,
                              hipStream_t stream)
{
    const float* x     = (const float*)d_in[0];
    const float* gW    = (const float*)d_in[1];
    const float* gb    = (const float*)d_in[2];
    const float* pW    = (const float*)d_in[3];
    const float* pb    = (const float*)d_in[4];
    const float* tW    = (const float*)d_in[5];
    const float* tb    = (const float*)d_in[6];
    const float* wW    = (const float*)d_in[7];
    const float* wb    = (const float*)d_in[8];
    const float* gamma = (const float*)d_in[9];
    const float* beta  = (const float*)d_in[10];
    float* out = (float*)d_out;

    char* w = (char*)d_ws;
    __hip_bfloat16* thetab = (__hip_bfloat16*)(w);                 // 1 MB
    __hip_bfloat16* phib   = (__hip_bfloat16*)(w + (1u<<20));      // 1 MB
    __hip_bfloat16* gtb    = (__hip_bfloat16*)(w + (2u<<20));      // 1 MB
    float* ypart = (float*)(w + (3u<<20));                         // 2 x 2 MB
    float* lpart = (float*)(w + (7u<<20));                         // 2 x 64 KB
    float* stats = (float*)(w + (7u<<20) + (1u<<18));              // 128 floats
    float* params = stats + 128;                                   // 128 floats

    hipMemsetAsync(stats, 0, 128*sizeof(float), stream);
    proj_kernel<<<256, 256, 0, stream>>>(x, gW, gb, pW, pb, tW, tb, thetab, phib, gtb);
    attn_kernel<<<512, 256, 0, stream>>>(thetab, phib, gtb, ypart, lpart);
    wy_kernel<<<128, 256, 0, stream>>>(ypart, ypart + (size_t)NPIX*32,
                                       lpart, lpart + NPIX,
                                       wW, wb, out, stats);
    bn_finalize<<<1, 64, 0, stream>>>(stats, gamma, beta, params);
    apply_kernel<<<1024, 256, 0, stream>>>(x, params, out);
}

// Round 2
// 89.273 us; speedup vs baseline: 1.1096x; 1.1096x over previous
//
#include <hip/hip_runtime.h>
#include <hip/hip_bf16.h>
#include <cstddef>
#include <cstdint>

#define NPIXT 16384          // 4*64*64
#define EPSV 1e-3f

using f32x4 = __attribute__((ext_vector_type(4))) float;
using bh8   = __attribute__((ext_vector_type(8))) short;   // 8 bf16

static __device__ __forceinline__ short bfs(float f) {
    __hip_bfloat16 h = __float2bfloat16(f);
    return *reinterpret_cast<short*>(&h);
}

// ---------------------------------------------------------------------------
// Kernel 1: projections. 512 blocks x 32 pixels. theta/phi: [pix][32] bf16.
// g stored PRE-SHUFFLED transposed: gshuf[b][d][4096] where within each
// 32-key chunk, position 8h+i holds key kappa(h,i)= i<4 ? 4h+i : 16+4h+(i-4).
// This matches the PV A-fragment key order so attn needs no transpose at all.
// ---------------------------------------------------------------------------
__global__ __launch_bounds__(256) void proj_kernel(
    const float* __restrict__ x,
    const float* __restrict__ gW, const float* __restrict__ gbias,
    const float* __restrict__ pW, const float* __restrict__ pbias,
    const float* __restrict__ tW, const float* __restrict__ tbias,
    __hip_bfloat16* __restrict__ thetab,
    __hip_bfloat16* __restrict__ phib,
    __hip_bfloat16* __restrict__ gshuf)
{
    __shared__ float lx[32*65];
    __shared__ float lw[3*2048];       // theta, phi, g weights [64c][32o]
    __shared__ float lbias[96];
    const int tid = threadIdx.x;
    const int pix0 = blockIdx.x * 32;

    #pragma unroll
    for (int j = 0; j < 8; ++j) {      // 2048 floats of x
        int idx = tid + 256*j;
        lx[(idx >> 6)*65 + (idx & 63)] = x[(size_t)pix0*64 + idx];
    }
    #pragma unroll
    for (int j = 0; j < 8; ++j) {
        int idx = tid + 256*j;
        lw[idx]        = tW[idx];
        lw[2048 + idx] = pW[idx];
        lw[4096 + idx] = gW[idx];
    }
    if (tid < 32) { lbias[tid] = tbias[tid]; lbias[32+tid] = pbias[tid]; lbias[64+tid] = gbias[tid]; }
    __syncthreads();

    const int p  = tid & 31;
    const int og = tid >> 5;           // 0..7 -> 12 outputs each (96 total)
    float xr[64];
    #pragma unroll
    for (int c = 0; c < 64; ++c) xr[c] = lx[p*65 + c];
    float acc[12];
    #pragma unroll
    for (int j = 0; j < 12; ++j) acc[j] = 0.f;
    const int obase = og*12;
    for (int c = 0; c < 64; ++c) {
        float xc = xr[c];
        #pragma unroll
        for (int j = 0; j < 12; ++j) {
            int o = obase + j;
            acc[j] += xc * lw[(o >> 5)*2048 + c*32 + (o & 31)];
        }
    }
    const int pix = pix0 + p;
    const int b = pix >> 12;
    const int n = pix & 4095;
    // pre-shuffled position for g
    const int loc = n & 31;
    const int t = (loc >> 4) & 1;
    const int hh = (loc >> 2) & 3;
    const int jj = loc & 3;
    const int pos = (n & ~31) + 8*hh + jj + 4*t;
    #pragma unroll
    for (int j = 0; j < 12; ++j) {
        int o = obase + j;
        __hip_bfloat16 bv = __float2bfloat16(acc[j] + lbias[o]);
        if (o < 32)       thetab[(size_t)pix*32 + o] = bv;
        else if (o < 64)  phib[(size_t)pix*32 + (o-32)] = bv;
        else              gshuf[((size_t)b*32 + (o-64))*4096 + pos] = bv;
    }
}

// ---------------------------------------------------------------------------
// Kernel 2: flash attention, max-free softmax, swapped-operand QK^T.
// 512 blocks (4 batch x 128 qtiles of 32 queries), 4 waves; wave w covers
// keys [w*1024, w*1024+1024). Two 16-query tiles share every K/G load.
// Lane (h=lane>>4, r=lane&15) after mfma(K,Q): S[k=16t+4h+gi][q=r] -> the
// exp'd values feed PV's A-fragment DIRECTLY (kmap baked into gshuf).
// Cross-wave combine in LDS, write normalized y [pix][32] f32.
// ---------------------------------------------------------------------------
__global__ __launch_bounds__(256, 4) void attn_kernel(
    const __hip_bfloat16* __restrict__ thetab,
    const __hip_bfloat16* __restrict__ phib,
    const __hip_bfloat16* __restrict__ gshuf,
    float* __restrict__ y)
{
    __shared__ float yl[4][32][33];
    __shared__ float lred[4][32];
    const int tid  = threadIdx.x;
    const int wave = tid >> 6;
    const int lane = tid & 63;
    const int h = lane >> 4;
    const int r = lane & 15;
    const int blk = blockIdx.x;
    const int b = blk >> 7;
    const int qtile = blk & 127;
    const int q0 = qtile * 32;
    const size_t base = (size_t)b * 4096;

    const bh8 qaA = *(const bh8*)(thetab + (base + q0 + r)*32 + h*8);
    const bh8 qaB = *(const bh8*)(thetab + (base + q0 + 16 + r)*32 + h*8);
    const __hip_bfloat16* phiB = phib  + base*32;
    const __hip_bfloat16* gB   = gshuf + base*32;

    f32x4 y0A = {0,0,0,0}, y1A = {0,0,0,0};
    f32x4 y0B = {0,0,0,0}, y1B = {0,0,0,0};
    float lsA = 0.f, lsB = 0.f;

    const int kbeg = wave * 1024;
    for (int kk = kbeg; kk < kbeg + 1024; kk += 32) {
        bh8 ka = *(const bh8*)(phiB + (size_t)(kk + r)*32 + h*8);
        bh8 kb = *(const bh8*)(phiB + (size_t)(kk + 16 + r)*32 + h*8);
        f32x4 z = {0,0,0,0};
        f32x4 s0A = __builtin_amdgcn_mfma_f32_16x16x32_bf16(ka, qaA, z, 0, 0, 0);
        f32x4 s1A = __builtin_amdgcn_mfma_f32_16x16x32_bf16(kb, qaA, z, 0, 0, 0);
        f32x4 s0B = __builtin_amdgcn_mfma_f32_16x16x32_bf16(ka, qaB, z, 0, 0, 0);
        f32x4 s1B = __builtin_amdgcn_mfma_f32_16x16x32_bf16(kb, qaB, z, 0, 0, 0);

        float pA0 = __expf(s0A[0]), pA1 = __expf(s0A[1]), pA2 = __expf(s0A[2]), pA3 = __expf(s0A[3]);
        float pA4 = __expf(s1A[0]), pA5 = __expf(s1A[1]), pA6 = __expf(s1A[2]), pA7 = __expf(s1A[3]);
        float pB0 = __expf(s0B[0]), pB1 = __expf(s0B[1]), pB2 = __expf(s0B[2]), pB3 = __expf(s0B[3]);
        float pB4 = __expf(s1B[0]), pB5 = __expf(s1B[1]), pB6 = __expf(s1B[2]), pB7 = __expf(s1B[3]);
        lsA += ((pA0+pA1)+(pA2+pA3)) + ((pA4+pA5)+(pA6+pA7));
        lsB += ((pB0+pB1)+(pB2+pB3)) + ((pB4+pB5)+(pB6+pB7));

        bh8 paA, paB;
        paA[0]=bfs(pA0); paA[1]=bfs(pA1); paA[2]=bfs(pA2); paA[3]=bfs(pA3);
        paA[4]=bfs(pA4); paA[5]=bfs(pA5); paA[6]=bfs(pA6); paA[7]=bfs(pA7);
        paB[0]=bfs(pB0); paB[1]=bfs(pB1); paB[2]=bfs(pB2); paB[3]=bfs(pB3);
        paB[4]=bfs(pB4); paB[5]=bfs(pB5); paB[6]=bfs(pB6); paB[7]=bfs(pB7);

        bh8 g0 = *(const bh8*)(gB + (size_t)r*4096 + kk + 8*h);
        bh8 g1 = *(const bh8*)(gB + (size_t)(16 + r)*4096 + kk + 8*h);
        y0A = __builtin_amdgcn_mfma_f32_16x16x32_bf16(paA, g0, y0A, 0, 0, 0);
        y1A = __builtin_amdgcn_mfma_f32_16x16x32_bf16(paA, g1, y1A, 0, 0, 0);
        y0B = __builtin_amdgcn_mfma_f32_16x16x32_bf16(paB, g0, y0B, 0, 0, 0);
        y1B = __builtin_amdgcn_mfma_f32_16x16x32_bf16(paB, g1, y1B, 0, 0, 0);
    }

    // l-sum: sum over h-groups (lanes differing in bits 4,5); all-query-r local
    lsA += __shfl_xor(lsA, 16); lsA += __shfl_xor(lsA, 32);
    lsB += __shfl_xor(lsB, 16); lsB += __shfl_xor(lsB, 32);

    #pragma unroll
    for (int gi = 0; gi < 4; ++gi) {
        yl[wave][4*h+gi][r]      = y0A[gi];
        yl[wave][4*h+gi][16+r]   = y1A[gi];
        yl[wave][16+4*h+gi][r]    = y0B[gi];
        yl[wave][16+4*h+gi][16+r] = y1B[gi];
    }
    if (lane < 16) { lred[wave][r] = lsA; lred[wave][16+r] = lsB; }
    __syncthreads();

    const int q  = tid >> 3;
    const int d4 = (tid & 7) * 4;
    float a0=0, a1=0, a2=0, a3=0;
    #pragma unroll
    for (int w = 0; w < 4; ++w) {
        a0 += yl[w][q][d4+0]; a1 += yl[w][q][d4+1];
        a2 += yl[w][q][d4+2]; a3 += yl[w][q][d4+3];
    }
    float lq = (lred[0][q] + lred[1][q]) + (lred[2][q] + lred[3][q]);
    float inv = 1.0f / lq;
    float4 res = { a0*inv, a1*inv, a2*inv, a3*inv };
    *(float4*)(y + (base + q0 + q)*32 + d4) = res;
}

// ---------------------------------------------------------------------------
// Kernel 3: w_y = y @ w_W + w_b -> out (pre-BN), per-block channel stats.
// 512 blocks x 32 pixels.
// ---------------------------------------------------------------------------
__global__ __launch_bounds__(256) void wy_kernel(
    const float* __restrict__ y,
    const float* __restrict__ wW, const float* __restrict__ wb,
    float* __restrict__ out, float* __restrict__ stats)
{
    __shared__ float ly[32*33];
    __shared__ float lwW[2048];
    __shared__ float lwb[64];
    __shared__ float wys[32*65];
    __shared__ float red1[256];
    __shared__ float red2[256];
    const int tid = threadIdx.x;
    const int pix0 = blockIdx.x * 32;

    #pragma unroll
    for (int j = 0; j < 4; ++j) {      // 1024 floats of y
        int idx = tid + 256*j;
        ly[(idx >> 5)*33 + (idx & 31)] = y[(size_t)pix0*32 + idx];
    }
    #pragma unroll
    for (int j = 0; j < 8; ++j) lwW[tid + 256*j] = wW[tid + 256*j];
    if (tid < 64) lwb[tid] = wb[tid];
    __syncthreads();

    const int p  = tid & 31;
    const int cg = tid >> 5;           // 0..7 -> channels cg*8..cg*8+7
    float acc[8];
    #pragma unroll
    for (int j = 0; j < 8; ++j) acc[j] = lwb[cg*8 + j];
    for (int d = 0; d < 32; ++d) {
        float yv = ly[p*33 + d];
        #pragma unroll
        for (int j = 0; j < 8; ++j) acc[j] += yv * lwW[d*64 + cg*8 + j];
    }
    #pragma unroll
    for (int j = 0; j < 8; ++j) wys[p*65 + cg*8 + j] = acc[j];
    float4 st0 = { acc[0], acc[1], acc[2], acc[3] };
    float4 st1 = { acc[4], acc[5], acc[6], acc[7] };
    *(float4*)(out + (size_t)(pix0 + p)*64 + cg*8)     = st0;
    *(float4*)(out + (size_t)(pix0 + p)*64 + cg*8 + 4) = st1;
    __syncthreads();

    const int c = tid & 63, grp = tid >> 6;
    float s1 = 0.f, s2 = 0.f;
    for (int pp = grp*8; pp < grp*8 + 8; ++pp) {
        float v = wys[pp*65 + c];
        s1 += v; s2 += v*v;
    }
    red1[grp*64 + c] = s1;
    red2[grp*64 + c] = s2;
    __syncthreads();
    if (tid < 64) {
        float t1 = red1[tid] + red1[64+tid] + red1[128+tid] + red1[192+tid];
        float t2 = red2[tid] + red2[64+tid] + red2[128+tid] + red2[192+tid];
        stats[(size_t)blockIdx.x*128 + tid]      = t1;
        stats[(size_t)blockIdx.x*128 + 64 + tid] = t2;
    }
}

// ---------------------------------------------------------------------------
// Kernel 4: reduce per-block stats (512 x 128) -> BN scale/shift per channel.
// ---------------------------------------------------------------------------
__global__ __launch_bounds__(256) void bn_finalize(
    const float* __restrict__ stats,
    const float* __restrict__ gamma,
    const float* __restrict__ beta,
    float* __restrict__ params)
{
    __shared__ float r1[256];
    __shared__ float r2[256];
    const int tid = threadIdx.x;
    const int c = tid & 63, part = tid >> 6;
    float s1 = 0.f, s2 = 0.f;
    for (int k = part*128; k < part*128 + 128; ++k) {
        s1 += stats[(size_t)k*128 + c];
        s2 += stats[(size_t)k*128 + 64 + c];
    }
    r1[part*64 + c] = s1;
    r2[part*64 + c] = s2;
    __syncthreads();
    if (tid < 64) {
        float t1 = r1[tid] + r1[64+tid] + r1[128+tid] + r1[192+tid];
        float t2 = r2[tid] + r2[64+tid] + r2[128+tid] + r2[192+tid];
        float mean = t1 * (1.0f/16384.0f);
        float var  = t2 * (1.0f/16384.0f) - mean*mean;
        float sc = gamma[tid] * rsqrtf(var + EPSV);
        params[tid]      = sc;
        params[64 + tid] = beta[tid] - mean*sc;
    }
}

// ---------------------------------------------------------------------------
// Kernel 5: out = x + scale[c]*w_y + shift[c]  (w_y currently in d_out)
// ---------------------------------------------------------------------------
__global__ __launch_bounds__(256) void apply_kernel(
    const float* __restrict__ x, const float* __restrict__ params,
    float* __restrict__ out)
{
    int i4 = blockIdx.x*256 + threadIdx.x;      // 262144 float4s
    const float4* x4 = (const float4*)x;
    float4* o4 = (float4*)out;
    int cb = (i4 & 15) * 4;
    float4 v  = o4[i4];
    float4 xv = x4[i4];
    float4 sc = *(const float4*)(params + cb);
    float4 sh = *(const float4*)(params + 64 + cb);
    float4 rr;
    rr.x = xv.x + sc.x*v.x + sh.x;
    rr.y = xv.y + sc.y*v.y + sh.y;
    rr.z = xv.z + sc.z*v.z + sh.z;
    rr.w = xv.w + sc.w*v.w + sh.w;
    o4[i4] = rr;
}

// ---------------------------------------------------------------------------
extern "C" void kernel_launch(void* const* d_in, const int* in_sizes, int n_in,
                              void* d_out, int out_size, void* d_ws, size_t ws_size,
                              hipStream_t stream)
{
    const float* x     = (const float*)d_in[0];
    const float* gW    = (const float*)d_in[1];
    const float* gb    = (const float*)d_in[2];
    const float* pW    = (const float*)d_in[3];
    const float* pb    = (const float*)d_in[4];
    const float* tW    = (const float*)d_in[5];
    const float* tb    = (const float*)d_in[6];
    const float* wW    = (const float*)d_in[7];
    const float* wb    = (const float*)d_in[8];
    const float* gamma = (const float*)d_in[9];
    const float* beta  = (const float*)d_in[10];
    float* out = (float*)d_out;

    char* w = (char*)d_ws;
    __hip_bfloat16* thetab = (__hip_bfloat16*)(w);                 // 1 MB
    __hip_bfloat16* phib   = (__hip_bfloat16*)(w + (1u<<20));      // 1 MB
    __hip_bfloat16* gshuf  = (__hip_bfloat16*)(w + (2u<<20));      // 1 MB
    float* y      = (float*)(w + (3u<<20));                        // 2 MB
    float* stats  = (float*)(w + (5u<<20));                        // 256 KB
    float* params = (float*)(w + (5u<<20) + (512u*128u*4u));       // 512 B

    proj_kernel<<<512, 256, 0, stream>>>(x, gW, gb, pW, pb, tW, tb, thetab, phib, gshuf);
    attn_kernel<<<512, 256, 0, stream>>>(thetab, phib, gshuf, y);
    wy_kernel<<<512, 256, 0, stream>>>(y, wW, wb, out, stats);
    bn_finalize<<<1, 256, 0, stream>>>(stats, gamma, beta, params);
    apply_kernel<<<1024, 256, 0, stream>>>(x, params, out);
}

// Round 3
// 79.805 us; speedup vs baseline: 1.2412x; 1.1186x over previous
//
#include <hip/hip_runtime.h>
#include <hip/hip_bf16.h>
#include <cstddef>
#include <cstdint>

#define EPSV 1e-3f

using f32x4 = __attribute__((ext_vector_type(4))) float;
using bh8   = __attribute__((ext_vector_type(8))) short;   // 8 bf16

static __device__ __forceinline__ short bfs(float f) {
    __hip_bfloat16 h = __float2bfloat16(f);
    return *reinterpret_cast<short*>(&h);
}

// ---------------------------------------------------------------------------
// Kernel 1: projections. 512 blocks x 32 pixels. theta/phi: [pix][32] bf16.
// g stored PRE-SHUFFLED transposed: gshuf[b][d][4096]; within each 32-key
// chunk, position 8h+i holds key kappa(h,i) = i<4 ? 4h+i : 16+4h+(i-4),
// matching the PV A-fragment key order (verified by rounds 1-2 passing).
// ---------------------------------------------------------------------------
__global__ __launch_bounds__(256) void proj_kernel(
    const float* __restrict__ x,
    const float* __restrict__ gW, const float* __restrict__ gbias,
    const float* __restrict__ pW, const float* __restrict__ pbias,
    const float* __restrict__ tW, const float* __restrict__ tbias,
    __hip_bfloat16* __restrict__ thetab,
    __hip_bfloat16* __restrict__ phib,
    __hip_bfloat16* __restrict__ gshuf)
{
    __shared__ float lx[32*65];
    __shared__ float lw[3*2048];       // theta, phi, g weights [64c][32o]
    __shared__ float lbias[96];
    const int tid = threadIdx.x;
    const int pix0 = blockIdx.x * 32;

    #pragma unroll
    for (int j = 0; j < 8; ++j) {      // 2048 floats of x
        int idx = tid + 256*j;
        lx[(idx >> 6)*65 + (idx & 63)] = x[(size_t)pix0*64 + idx];
    }
    #pragma unroll
    for (int j = 0; j < 8; ++j) {
        int idx = tid + 256*j;
        lw[idx]        = tW[idx];
        lw[2048 + idx] = pW[idx];
        lw[4096 + idx] = gW[idx];
    }
    if (tid < 32) { lbias[tid] = tbias[tid]; lbias[32+tid] = pbias[tid]; lbias[64+tid] = gbias[tid]; }
    __syncthreads();

    const int p  = tid & 31;
    const int og = tid >> 5;           // 0..7 -> 12 outputs each (96 total)
    const int obase = og*12;
    float acc[12];
    #pragma unroll
    for (int j = 0; j < 12; ++j) acc[j] = 0.f;
    for (int c = 0; c < 64; ++c) {
        float xc = lx[p*65 + c];
        #pragma unroll
        for (int j = 0; j < 12; ++j) {
            int o = obase + j;
            acc[j] += xc * lw[(o >> 5)*2048 + c*32 + (o & 31)];
        }
    }
    const int pix = pix0 + p;
    const int b = pix >> 12;
    const int n = pix & 4095;
    const int loc = n & 31;
    const int t = (loc >> 4) & 1;
    const int hh = (loc >> 2) & 3;
    const int jj = loc & 3;
    const int pos = (n & ~31) + 8*hh + jj + 4*t;
    #pragma unroll
    for (int j = 0; j < 12; ++j) {
        int o = obase + j;
        __hip_bfloat16 bv = __float2bfloat16(acc[j] + lbias[o]);
        if (o < 32)       thetab[(size_t)pix*32 + o] = bv;
        else if (o < 64)  phib[(size_t)pix*32 + (o-32)] = bv;
        else              gshuf[((size_t)b*32 + (o-64))*4096 + pos] = bv;
    }
}

// ---------------------------------------------------------------------------
// Kernel 2: fused flash-attention + output conv + BN partial stats.
// 512 blocks (4 batch x 128 qtiles of 32 queries), 4 waves; wave w covers
// keys [w*1024, w*1024+1024). Swapped-operand QK^T (mfma(K,Q)) makes exp'd
// scores a direct PV A-fragment (kmap baked into gshuf). Cross-wave combine
// in LDS -> normalized y tile -> y @ w_W + w_b -> out, plus per-block
// channel sum/sumsq partials via shfl reduction.
// ---------------------------------------------------------------------------
__global__ __launch_bounds__(256) void attn_kernel(
    const __hip_bfloat16* __restrict__ thetab,
    const __hip_bfloat16* __restrict__ phib,
    const __hip_bfloat16* __restrict__ gshuf,
    const float* __restrict__ wW, const float* __restrict__ wb,
    float* __restrict__ out, float* __restrict__ stats)
{
    __shared__ float yl[4][32][33];
    __shared__ float lred[4][32];
    __shared__ float lwW[2048];
    __shared__ float lwb[64];
    const int tid  = threadIdx.x;
    const int wave = tid >> 6;
    const int lane = tid & 63;
    const int h = lane >> 4;
    const int r = lane & 15;
    const int blk = blockIdx.x;
    const int b = blk >> 7;
    const int qtile = blk & 127;
    const int q0 = qtile * 32;
    const size_t base = (size_t)b * 4096;

    #pragma unroll
    for (int j = 0; j < 8; ++j) lwW[tid + 256*j] = wW[tid + 256*j];
    if (tid < 64) lwb[tid] = wb[tid];

    const bh8 qaA = *(const bh8*)(thetab + (base + q0 + r)*32 + h*8);
    const bh8 qaB = *(const bh8*)(thetab + (base + q0 + 16 + r)*32 + h*8);
    const __hip_bfloat16* phiB = phib  + base*32;
    const __hip_bfloat16* gB   = gshuf + base*32;

    f32x4 y0A = {0,0,0,0}, y1A = {0,0,0,0};
    f32x4 y0B = {0,0,0,0}, y1B = {0,0,0,0};
    float lsA = 0.f, lsB = 0.f;

    const int kbeg = wave * 1024;
    const int kend = kbeg + 1024;
    bh8 ka = *(const bh8*)(phiB + (size_t)(kbeg + r)*32 + h*8);
    bh8 kb = *(const bh8*)(phiB + (size_t)(kbeg + 16 + r)*32 + h*8);
    bh8 g0 = *(const bh8*)(gB + (size_t)r*4096 + kbeg + 8*h);
    bh8 g1 = *(const bh8*)(gB + (size_t)(16 + r)*4096 + kbeg + 8*h);

    for (int kk = kbeg; kk < kend; kk += 32) {
        const int nk = (kk + 32 < kend) ? (kk + 32) : kbeg;   // depth-1 prefetch
        bh8 ka2 = *(const bh8*)(phiB + (size_t)(nk + r)*32 + h*8);
        bh8 kb2 = *(const bh8*)(phiB + (size_t)(nk + 16 + r)*32 + h*8);
        bh8 g02 = *(const bh8*)(gB + (size_t)r*4096 + nk + 8*h);
        bh8 g12 = *(const bh8*)(gB + (size_t)(16 + r)*4096 + nk + 8*h);

        f32x4 z = {0,0,0,0};
        f32x4 s0A = __builtin_amdgcn_mfma_f32_16x16x32_bf16(ka, qaA, z, 0, 0, 0);
        f32x4 s1A = __builtin_amdgcn_mfma_f32_16x16x32_bf16(kb, qaA, z, 0, 0, 0);
        f32x4 s0B = __builtin_amdgcn_mfma_f32_16x16x32_bf16(ka, qaB, z, 0, 0, 0);
        f32x4 s1B = __builtin_amdgcn_mfma_f32_16x16x32_bf16(kb, qaB, z, 0, 0, 0);

        float pA0 = __expf(s0A[0]), pA1 = __expf(s0A[1]), pA2 = __expf(s0A[2]), pA3 = __expf(s0A[3]);
        float pA4 = __expf(s1A[0]), pA5 = __expf(s1A[1]), pA6 = __expf(s1A[2]), pA7 = __expf(s1A[3]);
        float pB0 = __expf(s0B[0]), pB1 = __expf(s0B[1]), pB2 = __expf(s0B[2]), pB3 = __expf(s0B[3]);
        float pB4 = __expf(s1B[0]), pB5 = __expf(s1B[1]), pB6 = __expf(s1B[2]), pB7 = __expf(s1B[3]);
        lsA += ((pA0+pA1)+(pA2+pA3)) + ((pA4+pA5)+(pA6+pA7));
        lsB += ((pB0+pB1)+(pB2+pB3)) + ((pB4+pB5)+(pB6+pB7));

        bh8 paA, paB;
        paA[0]=bfs(pA0); paA[1]=bfs(pA1); paA[2]=bfs(pA2); paA[3]=bfs(pA3);
        paA[4]=bfs(pA4); paA[5]=bfs(pA5); paA[6]=bfs(pA6); paA[7]=bfs(pA7);
        paB[0]=bfs(pB0); paB[1]=bfs(pB1); paB[2]=bfs(pB2); paB[3]=bfs(pB3);
        paB[4]=bfs(pB4); paB[5]=bfs(pB5); paB[6]=bfs(pB6); paB[7]=bfs(pB7);

        y0A = __builtin_amdgcn_mfma_f32_16x16x32_bf16(paA, g0, y0A, 0, 0, 0);
        y1A = __builtin_amdgcn_mfma_f32_16x16x32_bf16(paA, g1, y1A, 0, 0, 0);
        y0B = __builtin_amdgcn_mfma_f32_16x16x32_bf16(paB, g0, y0B, 0, 0, 0);
        y1B = __builtin_amdgcn_mfma_f32_16x16x32_bf16(paB, g1, y1B, 0, 0, 0);

        ka = ka2; kb = kb2; g0 = g02; g1 = g12;
    }

    lsA += __shfl_xor(lsA, 16); lsA += __shfl_xor(lsA, 32);
    lsB += __shfl_xor(lsB, 16); lsB += __shfl_xor(lsB, 32);

    #pragma unroll
    for (int gi = 0; gi < 4; ++gi) {
        yl[wave][4*h+gi][r]       = y0A[gi];
        yl[wave][4*h+gi][16+r]    = y1A[gi];
        yl[wave][16+4*h+gi][r]    = y0B[gi];
        yl[wave][16+4*h+gi][16+r] = y1B[gi];
    }
    if (lane < 16) { lred[wave][r] = lsA; lred[wave][16+r] = lsB; }
    __syncthreads();

    // Phase B: combine waves + normalize -> yl[0][q][d] (each thread reads
    // and writes only its own (q, d4..d4+3) elements; no cross-thread hazard)
    {
        const int q  = tid >> 3;
        const int d4 = (tid & 7) * 4;
        float a0=0, a1=0, a2=0, a3=0;
        #pragma unroll
        for (int w = 0; w < 4; ++w) {
            a0 += yl[w][q][d4+0]; a1 += yl[w][q][d4+1];
            a2 += yl[w][q][d4+2]; a3 += yl[w][q][d4+3];
        }
        float lq = (lred[0][q] + lred[1][q]) + (lred[2][q] + lred[3][q]);
        float inv = 1.0f / lq;
        yl[0][q][d4+0] = a0*inv;
        yl[0][q][d4+1] = a1*inv;
        yl[0][q][d4+2] = a2*inv;
        yl[0][q][d4+3] = a3*inv;
    }
    __syncthreads();

    // Phase C: w_y = y @ w_W + w_b -> out; channel sum/sumsq partials.
    {
        const int p  = tid & 31;
        const int cg = tid >> 5;           // 0..7 -> channels cg*8..cg*8+7
        float acc[8];
        #pragma unroll
        for (int j = 0; j < 8; ++j) acc[j] = lwb[cg*8 + j];
        for (int d = 0; d < 32; ++d) {
            float yv = yl[0][p][d];
            #pragma unroll
            for (int j = 0; j < 8; ++j) acc[j] += yv * lwW[d*64 + cg*8 + j];
        }
        float4 st0 = { acc[0], acc[1], acc[2], acc[3] };
        float4 st1 = { acc[4], acc[5], acc[6], acc[7] };
        *(float4*)(out + (size_t)(base + q0 + p)*64 + cg*8)     = st0;
        *(float4*)(out + (size_t)(base + q0 + p)*64 + cg*8 + 4) = st1;

        float s1[8], s2[8];
        #pragma unroll
        for (int j = 0; j < 8; ++j) { s1[j] = acc[j]; s2[j] = acc[j]*acc[j]; }
        #pragma unroll
        for (int m = 1; m <= 16; m <<= 1) {
            #pragma unroll
            for (int j = 0; j < 8; ++j) {
                s1[j] += __shfl_xor(s1[j], m);
                s2[j] += __shfl_xor(s2[j], m);
            }
        }
        if (p == 0) {
            #pragma unroll
            for (int j = 0; j < 8; ++j) {
                stats[(size_t)blk*128 + cg*8 + j]      = s1[j];
                stats[(size_t)blk*128 + 64 + cg*8 + j] = s2[j];
            }
        }
    }
}

// ---------------------------------------------------------------------------
// Kernel 3: reduce per-block stats (512 x 128) -> BN scale/shift per channel.
// ---------------------------------------------------------------------------
__global__ __launch_bounds__(256) void bn_finalize(
    const float* __restrict__ stats,
    const float* __restrict__ gamma,
    const float* __restrict__ beta,
    float* __restrict__ params)
{
    __shared__ float r1[256];
    __shared__ float r2[256];
    const int tid = threadIdx.x;
    const int c = tid & 63, part = tid >> 6;
    float s1 = 0.f, s2 = 0.f;
    for (int k = part*128; k < part*128 + 128; ++k) {
        s1 += stats[(size_t)k*128 + c];
        s2 += stats[(size_t)k*128 + 64 + c];
    }
    r1[part*64 + c] = s1;
    r2[part*64 + c] = s2;
    __syncthreads();
    if (tid < 64) {
        float t1 = r1[tid] + r1[64+tid] + r1[128+tid] + r1[192+tid];
        float t2 = r2[tid] + r2[64+tid] + r2[128+tid] + r2[192+tid];
        float mean = t1 * (1.0f/16384.0f);
        float var  = t2 * (1.0f/16384.0f) - mean*mean;
        float sc = gamma[tid] * rsqrtf(var + EPSV);
        params[tid]      = sc;
        params[64 + tid] = beta[tid] - mean*sc;
    }
}

// ---------------------------------------------------------------------------
// Kernel 4: out = x + scale[c]*w_y + shift[c]  (w_y currently in d_out)
// ---------------------------------------------------------------------------
__global__ __launch_bounds__(256) void apply_kernel(
    const float* __restrict__ x, const float* __restrict__ params,
    float* __restrict__ out)
{
    int i4 = blockIdx.x*256 + threadIdx.x;      // 262144 float4s
    const float4* x4 = (const float4*)x;
    float4* o4 = (float4*)out;
    int cb = (i4 & 15) * 4;
    float4 v  = o4[i4];
    float4 xv = x4[i4];
    float4 sc = *(const float4*)(params + cb);
    float4 sh = *(const float4*)(params + 64 + cb);
    float4 rr;
    rr.x = xv.x + sc.x*v.x + sh.x;
    rr.y = xv.y + sc.y*v.y + sh.y;
    rr.z = xv.z + sc.z*v.z + sh.z;
    rr.w = xv.w + sc.w*v.w + sh.w;
    o4[i4] = rr;
}

// ---------------------------------------------------------------------------
extern "C" void kernel_launch(void* const* d_in, const int* in_sizes, int n_in,
                              void* d_out, int out_size, void* d_ws, size_t ws_size,
                              hipStream_t stream)
{
    const float* x     = (const float*)d_in[0];
    const float* gW    = (const float*)d_in[1];
    const float* gb    = (const float*)d_in[2];
    const float* pW    = (const float*)d_in[3];
    const float* pb    = (const float*)d_in[4];
    const float* tW    = (const float*)d_in[5];
    const float* tb    = (const float*)d_in[6];
    const float* wW    = (const float*)d_in[7];
    const float* wb    = (const float*)d_in[8];
    const float* gamma = (const float*)d_in[9];
    const float* beta  = (const float*)d_in[10];
    float* out = (float*)d_out;

    char* w = (char*)d_ws;
    __hip_bfloat16* thetab = (__hip_bfloat16*)(w);                 // 1 MB
    __hip_bfloat16* phib   = (__hip_bfloat16*)(w + (1u<<20));      // 1 MB
    __hip_bfloat16* gshuf  = (__hip_bfloat16*)(w + (2u<<20));      // 1 MB
    float* stats  = (float*)(w + (3u<<20));                        // 256 KB
    float* params = (float*)(w + (3u<<20) + (512u*128u*4u));       // 512 B

    proj_kernel<<<512, 256, 0, stream>>>(x, gW, gb, pW, pb, tW, tb, thetab, phib, gshuf);
    attn_kernel<<<512, 256, 0, stream>>>(thetab, phib, gshuf, wW, wb, out, stats);
    bn_finalize<<<1, 256, 0, stream>>>(stats, gamma, beta, params);
    apply_kernel<<<1024, 256, 0, stream>>>(x, params, out);
}